// Round 3
// baseline (70.051 us; speedup 1.0000x reference)
//
#include <hip/hip_runtime.h>
#include <cstdint>
#include <cstddef>

// Problem constants (match reference: B, L, V, D = 1024, 200, 32000, 768)
#define NB 1024
#define NL 200
#define NV 32000
#define ND 768

// ---------------------------------------------------------------------------
// bf16 pack helpers (round-to-nearest-even; absmax ~4e-3 vs 1.3e-2 threshold)
// ---------------------------------------------------------------------------
__device__ __forceinline__ uint32_t rne_bf16(float f) {
    uint32_t u = __float_as_uint(f);
    return (u + 0x7fffu + ((u >> 16) & 1u)) >> 16;
}
__device__ __forceinline__ uint32_t pack2_bf16(float lo, float hi) {
    return rne_bf16(lo) | (rne_bf16(hi) << 16);
}
// unpack a u32 holding bf16 pair {lo=d even, hi=d odd} and accumulate
__device__ __forceinline__ void acc2(float* a, uint32_t p) {
    a[0] += __uint_as_float(p << 16);
    a[1] += __uint_as_float(p & 0xffff0000u);
}

// ---------------------------------------------------------------------------
// Kernel 1: transpose + convert  W[D, V] f32  ->  Wt[V, D] bf16 (u32 pairs).
// 64x64 tile in LDS (pad +1 -> 2-way conflicts only = free). Reads coalesced
// along v; writes coalesced along d. ~BW-bound at ~6.2 TB/s (R1/R2 measured).
// ---------------------------------------------------------------------------
__global__ __launch_bounds__(256) void transpose_convert_W(const float* __restrict__ W,
                                                           uint32_t* __restrict__ Wt32) {
    __shared__ float tile[64][65];
    const int v0 = blockIdx.x * 64;
    const int d0 = blockIdx.y * 64;
    const int tx = threadIdx.x;  // 0..63 along v
    const int ty = threadIdx.y;  // 0..3

#pragma unroll
    for (int i = 0; i < 64; i += 4) {
        tile[ty + i][tx] = W[(size_t)(d0 + ty + i) * NV + (v0 + tx)];
    }
    __syncthreads();

    const int tid = ty * 64 + tx;
    const int j = tid & 31;   // d-pair index within tile (d = d0 + 2j, 2j+1)
    const int r = tid >> 5;   // v-row subgroup 0..7
#pragma unroll
    for (int i = 0; i < 64; i += 8) {
        const int vloc = r + i;
        const float lo = tile[2 * j][vloc];
        const float hi = tile[2 * j + 1][vloc];
        Wt32[(size_t)(v0 + vloc) * (ND / 2) + (d0 >> 1) + j] = pack2_bf16(lo, hi);
    }
}

// ---------------------------------------------------------------------------
// Kernel 2: per-doc gather-sum over bf16 Wt.
// 384 threads = 4 token-groups x 96 chunk-threads; each thread owns 8 d's
// (one 16 B uint4 = 8 bf16) and 50 tokens.  Token loop unrolled 5x -> 5
// independent 16 B loads in flight per thread (MLP experiment: discriminates
// latency-limited vs L3-BW-limited).  f32 accumulate; LDS reduce; mask.
// ---------------------------------------------------------------------------
__global__ __launch_bounds__(384) void gather_rows_bf16(const int* __restrict__ tok,
                                                        const uint32_t* __restrict__ Wt32,
                                                        const float* __restrict__ bias,
                                                        float* __restrict__ out) {
    __shared__ int toks[NL];
    __shared__ float part[4][ND];
    __shared__ float wsum[3];

    const int doc = blockIdx.x;
    const int tid = threadIdx.x;
    const int g = tid / 96;   // token group 0..3
    const int c = tid % 96;   // 8-wide d-chunk 0..95

    if (tid < NL) {
        toks[tid] = tok[(size_t)doc * NL + tid];
    }
    __syncthreads();

    float acc[8] = {0.f, 0.f, 0.f, 0.f, 0.f, 0.f, 0.f, 0.f};
    const int tbase = g * 50;
    const uint4* __restrict__ wt4 = (const uint4*)Wt32;  // row stride ND/8 uint4

#pragma unroll 1
    for (int i = 0; i < 50; i += 5) {
        const int t0 = toks[tbase + i + 0];
        const int t1 = toks[tbase + i + 1];
        const int t2 = toks[tbase + i + 2];
        const int t3 = toks[tbase + i + 3];
        const int t4 = toks[tbase + i + 4];
        const uint4 p0 = wt4[(size_t)t0 * (ND / 8) + c];
        const uint4 p1 = wt4[(size_t)t1 * (ND / 8) + c];
        const uint4 p2 = wt4[(size_t)t2 * (ND / 8) + c];
        const uint4 p3 = wt4[(size_t)t3 * (ND / 8) + c];
        const uint4 p4 = wt4[(size_t)t4 * (ND / 8) + c];
        acc2(acc + 0, p0.x); acc2(acc + 2, p0.y); acc2(acc + 4, p0.z); acc2(acc + 6, p0.w);
        acc2(acc + 0, p1.x); acc2(acc + 2, p1.y); acc2(acc + 4, p1.z); acc2(acc + 6, p1.w);
        acc2(acc + 0, p2.x); acc2(acc + 2, p2.y); acc2(acc + 4, p2.z); acc2(acc + 6, p2.w);
        acc2(acc + 0, p3.x); acc2(acc + 2, p3.y); acc2(acc + 4, p3.z); acc2(acc + 6, p3.w);
        acc2(acc + 0, p4.x); acc2(acc + 2, p4.y); acc2(acc + 4, p4.z); acc2(acc + 6, p4.w);
    }

    ((float4*)&part[g][c * 8])[0] = make_float4(acc[0], acc[1], acc[2], acc[3]);
    ((float4*)&part[g][c * 8])[1] = make_float4(acc[4], acc[5], acc[6], acc[7]);
    __syncthreads();

    if (tid < 192) {
        const int d0 = tid * 4;
        const float4 s0 = *(const float4*)&part[0][d0];
        const float4 s1 = *(const float4*)&part[1][d0];
        const float4 s2 = *(const float4*)&part[2][d0];
        const float4 s3 = *(const float4*)&part[3][d0];
        const float4 bv = ((const float4*)bias)[tid];
        float4 r;
        r.x = (s0.x + s1.x) + (s2.x + s3.x) + bv.x;
        r.y = (s0.y + s1.y) + (s2.y + s3.y) + bv.y;
        r.z = (s0.z + s1.z) + (s2.z + s3.z) + bv.z;
        r.w = (s0.w + s1.w) + (s2.w + s3.w) + bv.w;
        ((float4*)(out + (size_t)doc * ND))[tid] = r;

        float s = (r.x + r.y) + (r.z + r.w);
#pragma unroll
        for (int off = 32; off > 0; off >>= 1) {
            s += __shfl_down(s, off);
        }
        if ((tid & 63) == 0) wsum[tid >> 6] = s;
    }
    __syncthreads();
    if (tid == 0) {
        const float total = (wsum[0] + wsum[1]) + wsum[2];
        out[(size_t)NB * ND + doc] = (total == 0.0f) ? 1.0f : 0.0f;
    }
}

// ---------------------------------------------------------------------------
// Fallback (only if ws_size can't hold bf16 Wt): gather strided columns of W
// directly in f32.  Uncoalesced but correct.
// ---------------------------------------------------------------------------
__global__ __launch_bounds__(192) void gather_cols_direct(const int* __restrict__ tok,
                                                          const float* __restrict__ W,
                                                          const float* __restrict__ bias,
                                                          float* __restrict__ out) {
    __shared__ int toks[NL];
    __shared__ float partial[3];

    const int doc = blockIdx.x;
    const int tid = threadIdx.x;

    for (int i = tid; i < NL; i += 192) {
        toks[i] = tok[(size_t)doc * NL + i];
    }
    __syncthreads();

    float acc[4] = {0.f, 0.f, 0.f, 0.f};
#pragma unroll 1
    for (int i = 0; i < NL; ++i) {
        const int t = toks[i];
#pragma unroll
        for (int j = 0; j < 4; ++j) {
            acc[j] += W[(size_t)(tid * 4 + j) * NV + t];
        }
    }
#pragma unroll
    for (int j = 0; j < 4; ++j) acc[j] += bias[tid * 4 + j];

    ((float4*)(out + (size_t)doc * ND))[tid] = make_float4(acc[0], acc[1], acc[2], acc[3]);

    float s = (acc[0] + acc[1]) + (acc[2] + acc[3]);
#pragma unroll
    for (int off = 32; off > 0; off >>= 1) {
        s += __shfl_down(s, off);
    }
    if ((tid & 63) == 0) partial[tid >> 6] = s;
    __syncthreads();
    if (tid == 0) {
        const float total = (partial[0] + partial[1]) + partial[2];
        out[(size_t)NB * ND + doc] = (total == 0.0f) ? 1.0f : 0.0f;
    }
}

extern "C" void kernel_launch(void* const* d_in, const int* in_sizes, int n_in,
                              void* d_out, int out_size, void* d_ws, size_t ws_size,
                              hipStream_t stream) {
    const int*   tok  = (const int*)d_in[0];    // [B, L] int32
    const float* W    = (const float*)d_in[1];  // [D, V] float32
    const float* bias = (const float*)d_in[2];  // [D] float32
    float* out = (float*)d_out;                 // proj [B*D] then mask [B]

    const size_t wt_bytes = (size_t)NV * (ND / 2) * sizeof(uint32_t);  // 49 MB

    if (ws_size >= wt_bytes) {
        uint32_t* Wt32 = (uint32_t*)d_ws;  // [V, D/2] u32 (bf16 pairs)
        dim3 tgrid(NV / 64, ND / 64);      // 500 x 12
        dim3 tblock(64, 4);
        transpose_convert_W<<<tgrid, tblock, 0, stream>>>(W, Wt32);
        gather_rows_bf16<<<NB, 384, 0, stream>>>(tok, Wt32, bias, out);
    } else {
        gather_cols_direct<<<NB, 192, 0, stream>>>(tok, W, bias, out);
    }
}

// Round 4
// 69.298 us; speedup vs baseline: 1.0109x; 1.0109x over previous
//
#include <hip/hip_runtime.h>
#include <cstdint>
#include <cstddef>

// Problem constants (match reference: B, L, V, D = 1024, 200, 32000, 768)
#define NB 1024
#define NL 200
#define NV 32000
#define ND 768

// ---------------------------------------------------------------------------
// bf16 pack helpers (round-to-nearest-even; absmax ~4e-3 vs 1.3e-2 threshold)
// ---------------------------------------------------------------------------
__device__ __forceinline__ uint32_t rne_bf16(float f) {
    uint32_t u = __float_as_uint(f);
    return (u + 0x7fffu + ((u >> 16) & 1u)) >> 16;
}
__device__ __forceinline__ uint32_t pack2_bf16(float lo, float hi) {
    return rne_bf16(lo) | (rne_bf16(hi) << 16);
}
// unpack a u32 holding bf16 pair {lo=d even, hi=d odd} and accumulate
__device__ __forceinline__ void acc2(float* a, uint32_t p) {
    a[0] += __uint_as_float(p << 16);
    a[1] += __uint_as_float(p & 0xffff0000u);
}

// ---------------------------------------------------------------------------
// Kernel 1: transpose + convert  W[D, V] f32  ->  Wt[V, D] bf16 (u32 pairs).
// 64x64 tile in LDS (pad +1 -> 2-way conflicts only = free). Reads coalesced
// along v; writes coalesced along d. BW-bound: 147 MB ~ 23 us.
// ---------------------------------------------------------------------------
__global__ __launch_bounds__(256) void transpose_convert_W(const float* __restrict__ W,
                                                           uint32_t* __restrict__ Wt32) {
    __shared__ float tile[64][65];
    const int v0 = blockIdx.x * 64;
    const int d0 = blockIdx.y * 64;
    const int tx = threadIdx.x;  // 0..63 along v
    const int ty = threadIdx.y;  // 0..3

#pragma unroll
    for (int i = 0; i < 64; i += 4) {
        tile[ty + i][tx] = W[(size_t)(d0 + ty + i) * NV + (v0 + tx)];
    }
    __syncthreads();

    const int tid = ty * 64 + tx;
    const int j = tid & 31;   // d-pair index within tile (d = d0 + 2j, 2j+1)
    const int r = tid >> 5;   // v-row subgroup 0..7
#pragma unroll
    for (int i = 0; i < 64; i += 8) {
        const int vloc = r + i;
        const float lo = tile[2 * j][vloc];
        const float hi = tile[2 * j + 1][vloc];
        Wt32[(size_t)(v0 + vloc) * (ND / 2) + (d0 >> 1) + j] = pack2_bf16(lo, hi);
    }
}

// ---------------------------------------------------------------------------
// Kernel 2: per-doc gather-sum over bf16 Wt.  (best-measured R2 variant;
// R3's deeper 5x unroll was null-to-negative -> BW-bound confirmed)
// 384 threads = 4 token-groups x 96 chunk-threads; each thread owns 8 d's
// (one 16 B uint4 = 8 bf16) and 50 tokens; f32 accumulate; LDS reduce the
// 4 partials; bias add; padding mask via wave shuffle.
// ---------------------------------------------------------------------------
__global__ __launch_bounds__(384) void gather_rows_bf16(const int* __restrict__ tok,
                                                        const uint32_t* __restrict__ Wt32,
                                                        const float* __restrict__ bias,
                                                        float* __restrict__ out) {
    __shared__ int toks[NL];
    __shared__ float part[4][ND];
    __shared__ float wsum[3];

    const int doc = blockIdx.x;
    const int tid = threadIdx.x;
    const int g = tid / 96;   // token group 0..3
    const int c = tid % 96;   // 8-wide d-chunk 0..95

    for (int i = tid; i < NL; i += 384) {
        toks[i] = tok[(size_t)doc * NL + i];
    }
    __syncthreads();

    float acc[8] = {0.f, 0.f, 0.f, 0.f, 0.f, 0.f, 0.f, 0.f};
    const int tbase = g * 50;

#pragma unroll 1
    for (int i = 0; i < 50; i += 2) {
        const int t0 = toks[tbase + i];
        const int t1 = toks[tbase + i + 1];
        const uint4 p0 = ((const uint4*)(Wt32 + (size_t)t0 * (ND / 2)))[c];
        const uint4 p1 = ((const uint4*)(Wt32 + (size_t)t1 * (ND / 2)))[c];
        acc2(acc + 0, p0.x); acc2(acc + 2, p0.y);
        acc2(acc + 4, p0.z); acc2(acc + 6, p0.w);
        acc2(acc + 0, p1.x); acc2(acc + 2, p1.y);
        acc2(acc + 4, p1.z); acc2(acc + 6, p1.w);
    }

    ((float4*)&part[g][c * 8])[0] = make_float4(acc[0], acc[1], acc[2], acc[3]);
    ((float4*)&part[g][c * 8])[1] = make_float4(acc[4], acc[5], acc[6], acc[7]);
    __syncthreads();

    if (tid < 192) {
        const int d0 = tid * 4;
        const float4 s0 = *(const float4*)&part[0][d0];
        const float4 s1 = *(const float4*)&part[1][d0];
        const float4 s2 = *(const float4*)&part[2][d0];
        const float4 s3 = *(const float4*)&part[3][d0];
        const float4 bv = ((const float4*)bias)[tid];
        float4 r;
        r.x = (s0.x + s1.x) + (s2.x + s3.x) + bv.x;
        r.y = (s0.y + s1.y) + (s2.y + s3.y) + bv.y;
        r.z = (s0.z + s1.z) + (s2.z + s3.z) + bv.z;
        r.w = (s0.w + s1.w) + (s2.w + s3.w) + bv.w;
        ((float4*)(out + (size_t)doc * ND))[tid] = r;

        float s = (r.x + r.y) + (r.z + r.w);
#pragma unroll
        for (int off = 32; off > 0; off >>= 1) {
            s += __shfl_down(s, off);
        }
        if ((tid & 63) == 0) wsum[tid >> 6] = s;
    }
    __syncthreads();
    if (tid == 0) {
        const float total = (wsum[0] + wsum[1]) + wsum[2];
        out[(size_t)NB * ND + doc] = (total == 0.0f) ? 1.0f : 0.0f;
    }
}

// ---------------------------------------------------------------------------
// Fallback (only if ws_size can't hold bf16 Wt): gather strided columns of W
// directly in f32.  Uncoalesced but correct.
// ---------------------------------------------------------------------------
__global__ __launch_bounds__(192) void gather_cols_direct(const int* __restrict__ tok,
                                                          const float* __restrict__ W,
                                                          const float* __restrict__ bias,
                                                          float* __restrict__ out) {
    __shared__ int toks[NL];
    __shared__ float partial[3];

    const int doc = blockIdx.x;
    const int tid = threadIdx.x;

    for (int i = tid; i < NL; i += 192) {
        toks[i] = tok[(size_t)doc * NL + i];
    }
    __syncthreads();

    float acc[4] = {0.f, 0.f, 0.f, 0.f};
#pragma unroll 1
    for (int i = 0; i < NL; ++i) {
        const int t = toks[i];
#pragma unroll
        for (int j = 0; j < 4; ++j) {
            acc[j] += W[(size_t)(tid * 4 + j) * NV + t];
        }
    }
#pragma unroll
    for (int j = 0; j < 4; ++j) acc[j] += bias[tid * 4 + j];

    ((float4*)(out + (size_t)doc * ND))[tid] = make_float4(acc[0], acc[1], acc[2], acc[3]);

    float s = (acc[0] + acc[1]) + (acc[2] + acc[3]);
#pragma unroll
    for (int off = 32; off > 0; off >>= 1) {
        s += __shfl_down(s, off);
    }
    if ((tid & 63) == 0) partial[tid >> 6] = s;
    __syncthreads();
    if (tid == 0) {
        const float total = (partial[0] + partial[1]) + partial[2];
        out[(size_t)NB * ND + doc] = (total == 0.0f) ? 1.0f : 0.0f;
    }
}

extern "C" void kernel_launch(void* const* d_in, const int* in_sizes, int n_in,
                              void* d_out, int out_size, void* d_ws, size_t ws_size,
                              hipStream_t stream) {
    const int*   tok  = (const int*)d_in[0];    // [B, L] int32
    const float* W    = (const float*)d_in[1];  // [D, V] float32
    const float* bias = (const float*)d_in[2];  // [D] float32
    float* out = (float*)d_out;                 // proj [B*D] then mask [B]

    const size_t wt_bytes = (size_t)NV * (ND / 2) * sizeof(uint32_t);  // 49 MB

    if (ws_size >= wt_bytes) {
        uint32_t* Wt32 = (uint32_t*)d_ws;  // [V, D/2] u32 (bf16 pairs)
        dim3 tgrid(NV / 64, ND / 64);      // 500 x 12
        dim3 tblock(64, 4);
        transpose_convert_W<<<tgrid, tblock, 0, stream>>>(W, Wt32);
        gather_rows_bf16<<<NB, 384, 0, stream>>>(tok, Wt32, bias, out);
    } else {
        gather_cols_direct<<<NB, 192, 0, stream>>>(tok, W, bias, out);
    }
}